// Round 6
// baseline (389.227 us; speedup 1.0000x reference)
//
#include <hip/hip_runtime.h>
#include <cfloat>
#include <math.h>

// Brute-force exact-replication KNN (k=10, +self) over 16384 3-D points, two
// instances, then M_i = max_j feats[nbr_rank_j, j-1], out = [feats | M-feats].
//
// NUMERICS ARE FROZEN (round-3 pass, absmax 0.0): XLA-consistent fp32 chains
//   sq  = fma(z,z, fma(y,y, rn(x*x)))
//   dot = fma(z,z', fma(y,y', rn(x*x')))   [same chain -> d_ii == 0.0 exactly]
//   d   = rn(rn(sq_i + sq_j) - rn(2*dot))
// Stable ascending-index insert == jax top_k tie-break; positional rank-0
// drop; M-v == subtract-then-max by rounding monotonicity. Do not alter.
//
// Round 6 (perf only): round 5's packed-fp32 idea, minus the inline asm that
// caused the regression (asm blocked scheduling/regalloc -> v_mov bloat,
// +30% busy cycles). Native <2 x float> ops + __builtin_elementwise_fma give
// guaranteed IEEE-rn per-half bits AND let the backend emit v_pk_{mul,add,
// fma}_f32 with full scheduling freedom. Each lane evaluates candidates
// (2*lane, 2*lane+1); even/odd ballot masks are merge-popped in ascending
// global candidate index (tie-break preserved — proven absmax 0.0 in R5).
// SoA LDS tiles: one ds_read_b64 per coord pair (2-way bank alias = free).

#define N_PTS    16384
#define C_FEAT   64
#define KK       11          // K+1 including self
#define TILE     1024        // candidates staged per LDS tile (12 KB SoA)
#define WQ       4           // queries processed concurrently per wave
#define NWAVES   4
#define NTHREADS (NWAVES * 64)
#define QPB      (NWAVES * WQ)           // 16 queries per block

typedef float v2f __attribute__((ext_vector_type(2)));

__global__ __launch_bounds__(NTHREADS) void knn_pool_kernel(
    const float* __restrict__ src_f, const float* __restrict__ tgt_f,
    const float* __restrict__ src_c, const float* __restrict__ tgt_c,
    float* __restrict__ out)
{
    const int inst = blockIdx.x & 1;
    const float* __restrict__ feats  = inst ? tgt_f : src_f;
    const float* __restrict__ coords = inst ? tgt_c : src_c;
    float* __restrict__ outb = out + (size_t)inst * (size_t)N_PTS * (2 * C_FEAT);

    const int qblock = (blockIdx.x >> 1) * QPB;
    const int tid   = threadIdx.x;
    const int wave  = tid >> 6;
    const int lane  = tid & 63;
    const int lq    = lane >> 4;      // which query's list this lane belongs to
    const int lrank = lane & 15;      // rank within that list (valid if < KK)
    const bool inlist = (lrank < KK);
    const int upaddr = ((lane + 63) & 63) << 2;   // ds_bpermute addr: lane-1

    __shared__ __align__(16) float sx[TILE];
    __shared__ __align__(16) float sy[TILE];
    __shared__ __align__(16) float sz[TILE];

    const int q0 = qblock + wave * WQ;

    // Query coords + fp32 sq_i (frozen fma chain), splat to packed pairs.
    v2f qx2[WQ], qy2[WQ], qz2[WQ], qsq2[WQ];
    bool ingrp[WQ];
    #pragma unroll
    for (int q = 0; q < WQ; ++q) {
        const float x = coords[(q0 + q) * 3 + 0];
        const float y = coords[(q0 + q) * 3 + 1];
        const float z = coords[(q0 + q) * 3 + 2];
        const float s = __fmaf_rn(z, z, __fmaf_rn(y, y, __fmul_rn(x, x)));
        qx2[q]  = (v2f){x, x};
        qy2[q]  = (v2f){y, y};
        qz2[q]  = (v2f){z, z};
        qsq2[q] = (v2f){s, s};
        ingrp[q] = inlist && (lq == q);
    }
    const v2f mtwo = (v2f){-2.0f, -2.0f};

    // Lane-distributed sorted lists: lanes 16q..16q+10 hold (dist,idx),
    // ascending. worst[q] = current 11th-smallest (uniform).
    float ld = FLT_MAX;
    int   li = 0;
    float worst[WQ];
    #pragma unroll
    for (int q = 0; q < WQ; ++q) worst[q] = FLT_MAX;

    for (int t0 = 0; t0 < N_PTS; t0 += TILE) {
        __syncthreads();
        for (int p = tid; p < TILE; p += NTHREADS) {
            const float* cp = coords + (size_t)(t0 + p) * 3;
            sx[p] = cp[0]; sy[p] = cp[1]; sz[p] = cp[2];
        }
        __syncthreads();

        for (int b = 0; b < TILE; b += 128) {
            const int cp = b + (lane << 1);      // even candidate of the pair
            const v2f cx2 = *(const v2f*)&sx[cp];
            const v2f cy2 = *(const v2f*)&sy[cp];
            const v2f cz2 = *(const v2f*)&sz[cp];
            // csq = fma(z,z, fma(y,y, rn(x*x)))  [per half, guaranteed fma]
            v2f csq2 = cx2 * cx2;
            csq2 = __builtin_elementwise_fma(cy2, cy2, csq2);
            csq2 = __builtin_elementwise_fma(cz2, cz2, csq2);
            const int jbase = t0 + b;

            #pragma unroll
            for (int q = 0; q < WQ; ++q) {
                // dot chain (k = x,y,z ascending, same chain as sq).
                v2f dot2 = cx2 * qx2[q];
                dot2 = __builtin_elementwise_fma(cy2, qy2[q], dot2);
                dot2 = __builtin_elementwise_fma(cz2, qz2[q], dot2);
                const v2f sum2 = qsq2[q] + csq2;
                // d = rn(sum - 2*dot); 2*dot exact -> == rn(sum - rn(2*dot))
                const v2f d2 = __builtin_elementwise_fma(dot2, mtwo, sum2);

                unsigned long long m0 = __ballot(d2.x < worst[q]);
                unsigned long long m1 = __ballot(d2.y < worst[q]);
                while (m0 | m1) {   // pop in ascending global candidate index
                    const int l0 = m0 ? (int)__builtin_ctzll(m0) : 64;
                    const int l1 = m1 ? (int)__builtin_ctzll(m1) : 64;
                    const bool even = (l0 <= l1);  // 2*l0 < 2*l1+1  <=>  l0<=l1
                    const int sl = even ? l0 : l1;
                    if (even) m0 &= m0 - 1; else m1 &= m1 - 1;
                    const float nd = __int_as_float(__builtin_amdgcn_readlane(
                        __float_as_int(even ? d2.x : d2.y), sl));
                    if (nd < worst[q]) {   // recheck: worst tightens in-loop
                        const int nj = jbase + 2 * sl + (even ? 0 : 1);
                        // Sorted insert across lanes 16q..16q+10:
                        // entries <= nd stay; entries > nd shift up one;
                        // first shifting lane takes (nd, nj); tail drops.
                        const float pld = __int_as_float(
                            __builtin_amdgcn_ds_bpermute(upaddr, __float_as_int(ld)));
                        const int   pli =
                            __builtin_amdgcn_ds_bpermute(upaddr, li);
                        if (ingrp[q] && ld > nd) {
                            const bool first = (lrank == 0) || (pld <= nd);
                            ld = first ? nd : pld;
                            li = first ? nj : pli;
                        }
                        worst[q] = __int_as_float(__builtin_amdgcn_readlane(
                            __float_as_int(ld), q * 16 + (KK - 1)));
                    }
                }
            }
        }
    }

    // Rank 0 dropped (self, or a -1ulp near-twin — positional, like ref).
    // Ranks 1..10 map to feature columns 0..9.
    float fv = -FLT_MAX;
    if (inlist && lrank >= 1)
        fv = feats[(size_t)li * C_FEAT + (lrank - 1)];
    #pragma unroll
    for (int off = 1; off < 16; off <<= 1)   // max within 16-lane group
        fv = fmaxf(fv, __shfl_xor(fv, off));

    #pragma unroll
    for (int q = 0; q < WQ; ++q) {
        const float M   = __shfl(fv, q * 16);
        const int   row = q0 + q;
        const float v   = feats[(size_t)row * C_FEAT + lane];
        outb[(size_t)row * (2 * C_FEAT) + lane]          = v;
        outb[(size_t)row * (2 * C_FEAT) + C_FEAT + lane] = M - v;
    }
}

extern "C" void kernel_launch(void* const* d_in, const int* in_sizes, int n_in,
                              void* d_out, int out_size, void* d_ws, size_t ws_size,
                              hipStream_t stream) {
    const float* src_f = (const float*)d_in[0];
    const float* tgt_f = (const float*)d_in[1];
    const float* src_c = (const float*)d_in[2];
    const float* tgt_c = (const float*)d_in[3];
    float* out = (float*)d_out;

    dim3 grid(2 * (N_PTS / QPB));   // 2048 blocks: even=src, odd=tgt
    dim3 block(NTHREADS);           // 256 threads = 4 waves
    hipLaunchKernelGGL(knn_pool_kernel, grid, block, 0, stream,
                       src_f, tgt_f, src_c, tgt_c, out);
}

// Round 7
// 249.795 us; speedup vs baseline: 1.5582x; 1.5582x over previous
//
#include <hip/hip_runtime.h>
#include <cfloat>
#include <math.h>

// Brute-force exact-replication KNN (k=10, +self) over 16384 3-D points, two
// instances, then M_i = max_j feats[nbr_rank_j, j-1], out = [feats | M-feats].
//
// NUMERICS ARE FROZEN (round-3 pass, absmax 0.0): XLA-consistent fp32 chains
//   sq  = fma(z,z, fma(y,y, rn(x*x)))
//   dot = fma(z,z', fma(y,y', rn(x*x')))   [same chain -> d_ii == 0.0 exactly]
//   d   = rn(sq_i+sq_j) - 2*dot, computed as fma(dot,-2,sum) which is
//         bitwise == rn(rn(sq_i+sq_j) - rn(2*dot)) since 2*dot is exact
//         (device-verified in rounds 5/6, absmax 0.0).
// Stable ascending-index insert == jax top_k tie-break; positional rank-0
// drop; M-v == subtract-then-max by rounding monotonicity. Do not alter.
//
// Round 7 (perf only): back to the scalar R4 champion structure (272 us;
// v2f packing is a confirmed dead end — LLVM pads vector values with
// pack/unpack movs, +25% busy cycles). Changes vs R4:
//  - SoA LDS (sx/sy/sz): one vaddr, ds_read_b32 with immediate offsets
//    0/4096/8192 — kills the *3 address math per batch.
//  - d = fma(dot,-2f,sum): 1 inst instead of mul+sub (bit-identical, see
//    above).
//  - Insert path: readlane broadcasts (VALU, ~4cyc) instead of
//    __shfl->ds_bpermute (~40cyc serial); shfl_up via ds_bpermute with a
//    hoisted lane-1 address (correctness proven in R5/R6, absmax 0.0).
//  - Register double-buffer for tile staging: issue next tile's global
//    loads before the compute loop, write regs->LDS at the next barrier;
//    L2/L3 latency overlaps ~2000 cycles of compute instead of stalling
//    the block (attacks the ~100 us idle fraction).

#define N_PTS    16384
#define C_FEAT   64
#define KK       11          // K+1 including self
#define TILE     1024        // candidates per LDS tile (12 KB SoA)
#define LPT      (TILE / NTHREADS)       // staging loads per thread = 4
#define WQ       4           // queries processed concurrently per wave
#define NWAVES   4
#define NTHREADS (NWAVES * 64)
#define QPB      (NWAVES * WQ)           // 16 queries per block

__global__ __launch_bounds__(NTHREADS) void knn_pool_kernel(
    const float* __restrict__ src_f, const float* __restrict__ tgt_f,
    const float* __restrict__ src_c, const float* __restrict__ tgt_c,
    float* __restrict__ out)
{
    const int inst = blockIdx.x & 1;
    const float* __restrict__ feats  = inst ? tgt_f : src_f;
    const float* __restrict__ coords = inst ? tgt_c : src_c;
    float* __restrict__ outb = out + (size_t)inst * (size_t)N_PTS * (2 * C_FEAT);

    const int qblock = (blockIdx.x >> 1) * QPB;
    const int tid   = threadIdx.x;
    const int wave  = tid >> 6;
    const int lane  = tid & 63;
    const int lq    = lane >> 4;      // which query's list this lane belongs to
    const int lrank = lane & 15;      // rank within that list (valid if < KK)
    const bool inlist = (lrank < KK);
    const int upaddr = ((lane + 63) & 63) << 2;   // ds_bpermute addr: lane-1

    __shared__ __align__(16) float sx[TILE];   // LDS offset 0
    __shared__ __align__(16) float sy[TILE];   // LDS offset 4096
    __shared__ __align__(16) float sz[TILE];   // LDS offset 8192

    const int q0 = qblock + wave * WQ;

    // Query coords + fp32 sq_i (frozen fma chain).
    float qx[WQ], qy[WQ], qz[WQ], qsq[WQ];
    bool ingrp[WQ];
    #pragma unroll
    for (int q = 0; q < WQ; ++q) {
        qx[q] = coords[(q0 + q) * 3 + 0];
        qy[q] = coords[(q0 + q) * 3 + 1];
        qz[q] = coords[(q0 + q) * 3 + 2];
        qsq[q] = __fmaf_rn(qz[q], qz[q],
                 __fmaf_rn(qy[q], qy[q],
                 __fmul_rn(qx[q], qx[q])));
        ingrp[q] = inlist && (lq == q);
    }

    // Lane-distributed sorted lists: lanes 16q..16q+10 hold (dist,idx),
    // ascending. worst[q] = current 11th-smallest (uniform).
    float ld = FLT_MAX;
    int   li = 0;
    float worst[WQ];
    #pragma unroll
    for (int q = 0; q < WQ; ++q) worst[q] = FLT_MAX;

    // Staging registers: double-buffer tile t+1 while computing tile t.
    float rx[LPT], ry[LPT], rz[LPT];
    #pragma unroll
    for (int i = 0; i < LPT; ++i) {
        const float* cp = coords + (size_t)(tid + i * NTHREADS) * 3;
        rx[i] = cp[0]; ry[i] = cp[1]; rz[i] = cp[2];
    }

    for (int t0 = 0; t0 < N_PTS; t0 += TILE) {
        __syncthreads();   // previous tile's readers done
        #pragma unroll
        for (int i = 0; i < LPT; ++i) {   // regs -> LDS (vmcnt wait here)
            const int p = tid + i * NTHREADS;
            sx[p] = rx[i]; sy[p] = ry[i]; sz[p] = rz[i];
        }
        __syncthreads();
        if (t0 + TILE < N_PTS) {          // issue next tile's loads now;
            #pragma unroll                 // consumed at the next barrier
            for (int i = 0; i < LPT; ++i) {
                const float* cp = coords + (size_t)(t0 + TILE + tid + i * NTHREADS) * 3;
                rx[i] = cp[0]; ry[i] = cp[1]; rz[i] = cp[2];
            }
        }

        for (int b = 0; b < TILE; b += 64) {
            const int ci = b + lane;
            const float cx = sx[ci];   // one vaddr, imm offsets 0/4096/8192
            const float cy = sy[ci];
            const float cz = sz[ci];
            const float csq = __fmaf_rn(cz, cz,
                              __fmaf_rn(cy, cy,
                              __fmul_rn(cx, cx)));

            #pragma unroll
            for (int q = 0; q < WQ; ++q) {
                // dot: fma chain, k = x,y,z ascending (same chain as sq).
                float dot = __fmul_rn(cx, qx[q]);
                dot = __fmaf_rn(cy, qy[q], dot);
                dot = __fmaf_rn(cz, qz[q], dot);
                const float sum = __fadd_rn(qsq[q], csq);
                // d == rn(sum - rn(2*dot)); 2*dot exact (device-verified).
                const float d = __fmaf_rn(dot, -2.0f, sum);

                unsigned long long m = __ballot(d < worst[q]);
                while (m) {  // wave-uniform pop, ascending candidate idx
                    const int sl = (int)__builtin_ctzll(m);
                    m &= m - 1;
                    const float nd = __int_as_float(__builtin_amdgcn_readlane(
                        __float_as_int(d), sl));
                    if (nd < worst[q]) {   // recheck: worst tightens in-loop
                        const int nj = t0 + b + sl;
                        // Sorted insert across lanes 16q..16q+10:
                        // entries <= nd stay; entries > nd shift up one;
                        // first shifting lane takes (nd, nj); tail drops.
                        const float pld = __int_as_float(
                            __builtin_amdgcn_ds_bpermute(upaddr, __float_as_int(ld)));
                        const int   pli =
                            __builtin_amdgcn_ds_bpermute(upaddr, li);
                        if (ingrp[q] && ld > nd) {
                            const bool first = (lrank == 0) || (pld <= nd);
                            ld = first ? nd : pld;
                            li = first ? nj : pli;
                        }
                        worst[q] = __int_as_float(__builtin_amdgcn_readlane(
                            __float_as_int(ld), q * 16 + (KK - 1)));
                    }
                }
            }
        }
    }

    // Rank 0 dropped (self, or a -1ulp near-twin — positional, like ref).
    // Ranks 1..10 map to feature columns 0..9.
    float fv = -FLT_MAX;
    if (inlist && lrank >= 1)
        fv = feats[(size_t)li * C_FEAT + (lrank - 1)];
    #pragma unroll
    for (int off = 1; off < 16; off <<= 1)   // max within 16-lane group
        fv = fmaxf(fv, __shfl_xor(fv, off));

    #pragma unroll
    for (int q = 0; q < WQ; ++q) {
        const float M   = __shfl(fv, q * 16);
        const int   row = q0 + q;
        const float v   = feats[(size_t)row * C_FEAT + lane];
        outb[(size_t)row * (2 * C_FEAT) + lane]          = v;
        outb[(size_t)row * (2 * C_FEAT) + C_FEAT + lane] = M - v;
    }
}

extern "C" void kernel_launch(void* const* d_in, const int* in_sizes, int n_in,
                              void* d_out, int out_size, void* d_ws, size_t ws_size,
                              hipStream_t stream) {
    const float* src_f = (const float*)d_in[0];
    const float* tgt_f = (const float*)d_in[1];
    const float* src_c = (const float*)d_in[2];
    const float* tgt_c = (const float*)d_in[3];
    float* out = (float*)d_out;

    dim3 grid(2 * (N_PTS / QPB));   // 2048 blocks: even=src, odd=tgt
    dim3 block(NTHREADS);           // 256 threads = 4 waves
    hipLaunchKernelGGL(knn_pool_kernel, grid, block, 0, stream,
                       src_f, tgt_f, src_c, tgt_c, out);
}